// Round 1
// 852.975 us; speedup vs baseline: 1.0808x; 1.0808x over previous
//
#include <hip/hip_runtime.h>

// Problem constants (fixed by the reference):
//   N0=200000, N1=50000, N2=10000, E0=1600000, E1=320000
//   IN_CH=256, HID=256, OUT=128,  K = 3*256 = 768
//
// Round 6: bucket_kernel was 153us with WRITE_SIZE=103MB (= E0 x 64B): every
// scattered 4B bsrc store dirties a full line, and with random dst all 8
// non-coherent XCD L2s dirty copies of the SAME lines -> 16x write
// amplification + coherence serialization on the pos[] atomics. Fix: XCD-
// partitioned bucketing. Blocks dispatch round-robin to XCDs (blockIdx%8),
// so block part=blockIdx&7 filters edges to dst-partition `part`. Each
// partition's cursor counters and its contiguous ~0.8MB bsrc range are then
// touched by exactly ONE XCD's L2 -> stores merge in L2 before writeback.
// Cost: 8x coalesced re-read of the edge list (~102MB, L3-resident).

typedef __attribute__((ext_vector_type(8))) short short8;
typedef __attribute__((ext_vector_type(4))) float float4v;

__device__ __forceinline__ unsigned short f2bf(float f) {
    union { float f; unsigned int u; } c; c.f = f;
    unsigned int r = (c.u + 0x7FFFu + ((c.u >> 16) & 1u)) >> 16;  // RNE
    return (unsigned short)r;
}
__device__ __forceinline__ float bf2f(unsigned short u) {
    union { unsigned int u; float f; } c; c.u = ((unsigned int)u) << 16;
    return c.f;
}

// ---------------------------------------------------------------------------
// fp32 -> bf16 streaming convert (4 elems/thread).
// ---------------------------------------------------------------------------
__global__ __launch_bounds__(256) void xcvt_kernel(
    const float* __restrict__ x, unsigned short* __restrict__ xb, int n4)
{
    int i = blockIdx.x * 256 + threadIdx.x;
    if (i < n4) {
        float4 v = ((const float4*)x)[i];
        ushort4 r;
        r.x = f2bf(v.x); r.y = f2bf(v.y); r.z = f2bf(v.z); r.w = f2bf(v.w);
        ((ushort4*)xb)[i] = r;
    }
}

// ---------------------------------------------------------------------------
// CSR build step 1: degree histogram, 4 edges/thread.
// ---------------------------------------------------------------------------
__global__ __launch_bounds__(256) void count_kernel(
    const int* __restrict__ dst, int* __restrict__ deg, int E)
{
    int i = (blockIdx.x * 256 + threadIdx.x) * 4;
    if (i + 3 < E) {
        int4 d = *(const int4*)&dst[i];
        atomicAdd(&deg[d.x], 1);
        atomicAdd(&deg[d.y], 1);
        atomicAdd(&deg[d.z], 1);
        atomicAdd(&deg[d.w], 1);
    } else {
        for (int k = i; k < E; k++) atomicAdd(&deg[dst[k]], 1);
    }
}

// ---------------------------------------------------------------------------
// CSR build step 2a: per-block (1024-elem) partial sums of deg.
// ---------------------------------------------------------------------------
__global__ __launch_bounds__(256) void partial_kernel(
    const int* __restrict__ deg, int* __restrict__ part, int n)
{
    __shared__ int sm[256];
    const int base = blockIdx.x * 1024;
    const int t = threadIdx.x;
    int s = 0;
#pragma unroll
    for (int i = 0; i < 4; i++) {
        int idx = base + t + i * 256;
        if (idx < n) s += deg[idx];
    }
    sm[t] = s;
    __syncthreads();
    for (int off = 128; off > 0; off >>= 1) {
        if (t < off) sm[t] += sm[t + off];
        __syncthreads();
    }
    if (t == 0) part[blockIdx.x] = sm[0];
}

// ---------------------------------------------------------------------------
// CSR build step 2b: exclusive scan of block partials (nb <= 256).
// ---------------------------------------------------------------------------
__global__ __launch_bounds__(256) void scanpart_kernel(
    int* __restrict__ part, int* __restrict__ rowptr, int nb, int n)
{
    __shared__ int sm[256];
    const int t = threadIdx.x;
    sm[t] = (t < nb) ? part[t] : 0;
    __syncthreads();
    if (t == 0) {
        int acc = 0;
        for (int i = 0; i < nb; i++) { int v = sm[i]; sm[i] = acc; acc += v; }
        rowptr[n] = acc;
    }
    __syncthreads();
    if (t < nb) part[t] = sm[t];
}

// ---------------------------------------------------------------------------
// CSR build step 2c: intra-block exclusive scan; rowptr + cursor init.
// ---------------------------------------------------------------------------
__global__ __launch_bounds__(256) void apply_kernel(
    int* __restrict__ deg, const int* __restrict__ part,
    int* __restrict__ rowptr, int n)
{
    __shared__ int sm[256];
    const int base = blockIdx.x * 1024;
    const int t = threadIdx.x;
    const int i0 = base + t * 4;

    int4 d = {0, 0, 0, 0};
    if (i0 + 3 < n) {
        d = *(const int4*)&deg[i0];
    } else {
        if (i0 + 0 < n) d.x = deg[i0 + 0];
        if (i0 + 1 < n) d.y = deg[i0 + 1];
        if (i0 + 2 < n) d.z = deg[i0 + 2];
        if (i0 + 3 < n) d.w = deg[i0 + 3];
    }
    const int ts = d.x + d.y + d.z + d.w;
    sm[t] = ts;
    __syncthreads();
    for (int off = 1; off < 256; off <<= 1) {
        int u = (t >= off) ? sm[t - off] : 0;
        __syncthreads();
        sm[t] += u;
        __syncthreads();
    }
    int pref = part[blockIdx.x] + sm[t] - ts;

    int p0 = pref;
    int p1 = p0 + d.x;
    int p2 = p1 + d.y;
    int p3 = p2 + d.z;
    if (i0 + 0 < n) { rowptr[i0 + 0] = p0; deg[i0 + 0] = p0; }
    if (i0 + 1 < n) { rowptr[i0 + 1] = p1; deg[i0 + 1] = p1; }
    if (i0 + 2 < n) { rowptr[i0 + 2] = p2; deg[i0 + 2] = p2; }
    if (i0 + 3 < n) { rowptr[i0 + 3] = p3; deg[i0 + 3] = p3; }
}

// ---------------------------------------------------------------------------
// CSR build step 3: bucket src ids by dst, XCD-partitioned.
// part = blockIdx&7 tracks the round-robin block->XCD mapping; this block
// only commits edges whose dst falls in partition `part`, so each
// partition's pos[] counters and contiguous bsrc range live in ONE L2.
// Edge list is re-read 8x (coalesced, L3-resident) -- cheap.
// ---------------------------------------------------------------------------
__global__ __launch_bounds__(256) void bucket_part_kernel(
    const int* __restrict__ src, const int* __restrict__ dst,
    int* __restrict__ pos, int* __restrict__ bsrc, int E, int ps)
{
    const int part = blockIdx.x & 7;
    const int lo = part * ps;
    const int hi = lo + ps;
    int i = ((blockIdx.x >> 3) * 256 + threadIdx.x) * 4;
    if (i + 3 < E) {
        int4 d = *(const int4*)&dst[i];
        int4 s = *(const int4*)&src[i];
        if (d.x >= lo && d.x < hi) { int p = atomicAdd(&pos[d.x], 1); bsrc[p] = s.x; }
        if (d.y >= lo && d.y < hi) { int p = atomicAdd(&pos[d.y], 1); bsrc[p] = s.y; }
        if (d.z >= lo && d.z < hi) { int p = atomicAdd(&pos[d.z], 1); bsrc[p] = s.z; }
        if (d.w >= lo && d.w < hi) { int p = atomicAdd(&pos[d.w], 1); bsrc[p] = s.w; }
    } else {
        for (int k = i; k < E; k++) {
            int dv = dst[k];
            if (dv >= lo && dv < hi) {
                int p = atomicAdd(&pos[dv], 1);
                bsrc[p] = src[k];
            }
        }
    }
}

// ---------------------------------------------------------------------------
// Aggregation, fp32 source -> bf16 mean (fallback path only).
// ---------------------------------------------------------------------------
__global__ __launch_bounds__(256) void agg_f32_kernel(
    const float* __restrict__ xsrc,
    const int* __restrict__ rowptr,
    const int* __restrict__ bsrc,
    unsigned short* __restrict__ outp,
    int pitch, int n)
{
    int row = blockIdx.x * 4 + (threadIdx.x >> 6);
    if (row >= n) return;
    const int lane = threadIdx.x & 63;
    const int beg = rowptr[row];
    const int end = rowptr[row + 1];

    float4 a0 = {0.f, 0.f, 0.f, 0.f};
    float4 a1 = {0.f, 0.f, 0.f, 0.f};
    float4 a2 = {0.f, 0.f, 0.f, 0.f};
    float4 a3 = {0.f, 0.f, 0.f, 0.f};
    int e = beg;
    for (; e + 3 < end; e += 4) {
        int s0 = bsrc[e + 0];
        int s1 = bsrc[e + 1];
        int s2 = bsrc[e + 2];
        int s3 = bsrc[e + 3];
        float4 v0 = ((const float4*)(xsrc + (size_t)s0 * 256))[lane];
        float4 v1 = ((const float4*)(xsrc + (size_t)s1 * 256))[lane];
        float4 v2 = ((const float4*)(xsrc + (size_t)s2 * 256))[lane];
        float4 v3 = ((const float4*)(xsrc + (size_t)s3 * 256))[lane];
        a0.x += v0.x; a0.y += v0.y; a0.z += v0.z; a0.w += v0.w;
        a1.x += v1.x; a1.y += v1.y; a1.z += v1.z; a1.w += v1.w;
        a2.x += v2.x; a2.y += v2.y; a2.z += v2.z; a2.w += v2.w;
        a3.x += v3.x; a3.y += v3.y; a3.z += v3.z; a3.w += v3.w;
    }
    for (; e < end; e++) {
        int s0 = bsrc[e];
        float4 v0 = ((const float4*)(xsrc + (size_t)s0 * 256))[lane];
        a0.x += v0.x; a0.y += v0.y; a0.z += v0.z; a0.w += v0.w;
    }
    float inv = 1.0f / fmaxf((float)(end - beg), 1.0f);
    ushort4 r;
    r.x = f2bf((a0.x + a1.x + a2.x + a3.x) * inv);
    r.y = f2bf((a0.y + a1.y + a2.y + a3.y) * inv);
    r.z = f2bf((a0.z + a1.z + a2.z + a3.z) * inv);
    r.w = f2bf((a0.w + a1.w + a2.w + a3.w) * inv);
    *(ushort4*)(outp + (size_t)row * pitch + lane * 4) = r;
}

// ---------------------------------------------------------------------------
// Aggregation, bf16 source -> bf16 mean. One wave per row, lane owns 4
// channels (8B loads -> 512B per row access), 4 edges in flight.
// ---------------------------------------------------------------------------
__global__ __launch_bounds__(256) void agg_bf16_kernel(
    const unsigned short* __restrict__ hsrc,  // [*, 256] bf16
    const int* __restrict__ rowptr,
    const int* __restrict__ bsrc,
    unsigned short* __restrict__ outp,
    int pitch, int n)
{
    int row = blockIdx.x * 4 + (threadIdx.x >> 6);
    if (row >= n) return;
    const int lane = threadIdx.x & 63;
    const int beg = rowptr[row];
    const int end = rowptr[row + 1];

    float4 a0 = {0.f, 0.f, 0.f, 0.f};
    float4 a1 = {0.f, 0.f, 0.f, 0.f};
    float4 a2 = {0.f, 0.f, 0.f, 0.f};
    float4 a3 = {0.f, 0.f, 0.f, 0.f};
    int e = beg;
    for (; e + 3 < end; e += 4) {
        int s0 = bsrc[e + 0];
        int s1 = bsrc[e + 1];
        int s2 = bsrc[e + 2];
        int s3 = bsrc[e + 3];
        ushort4 u0 = *(const ushort4*)(hsrc + (size_t)s0 * 256 + lane * 4);
        ushort4 u1 = *(const ushort4*)(hsrc + (size_t)s1 * 256 + lane * 4);
        ushort4 u2 = *(const ushort4*)(hsrc + (size_t)s2 * 256 + lane * 4);
        ushort4 u3 = *(const ushort4*)(hsrc + (size_t)s3 * 256 + lane * 4);
        a0.x += bf2f(u0.x); a0.y += bf2f(u0.y); a0.z += bf2f(u0.z); a0.w += bf2f(u0.w);
        a1.x += bf2f(u1.x); a1.y += bf2f(u1.y); a1.z += bf2f(u1.z); a1.w += bf2f(u1.w);
        a2.x += bf2f(u2.x); a2.y += bf2f(u2.y); a2.z += bf2f(u2.z); a2.w += bf2f(u2.w);
        a3.x += bf2f(u3.x); a3.y += bf2f(u3.y); a3.z += bf2f(u3.z); a3.w += bf2f(u3.w);
    }
    for (; e < end; e++) {
        int s0 = bsrc[e];
        ushort4 u0 = *(const ushort4*)(hsrc + (size_t)s0 * 256 + lane * 4);
        a0.x += bf2f(u0.x); a0.y += bf2f(u0.y); a0.z += bf2f(u0.z); a0.w += bf2f(u0.w);
    }
    float inv = 1.0f / fmaxf((float)(end - beg), 1.0f);
    ushort4 r;
    r.x = f2bf((a0.x + a1.x + a2.x + a3.x) * inv);
    r.y = f2bf((a0.y + a1.y + a2.y + a3.y) * inv);
    r.z = f2bf((a0.z + a1.z + a2.z + a3.z) * inv);
    r.w = f2bf((a0.w + a1.w + a2.w + a3.w) * inv);
    *(ushort4*)(outp + (size_t)row * pitch + lane * 4) = r;
}

// ---------------------------------------------------------------------------
// Pack seg1 (x_dst) + seg2 (0.25*attr[batch]). fp32-x variant (fallback).
// ---------------------------------------------------------------------------
__global__ __launch_bounds__(256) void pack0_kernel(
    const float* __restrict__ x, const float* __restrict__ attr,
    const int* __restrict__ batch, unsigned short* __restrict__ abuf, int n)
{
    int row = blockIdx.x * 4 + (threadIdx.x >> 6);
    if (row >= n) return;
    const int lane = threadIdx.x & 63;
    float4 xv = ((const float4*)(x + (size_t)row * 256))[lane];
    int b = batch[row];
    float4 av = ((const float4*)(attr + (size_t)b * 256))[lane];
    unsigned short* dst = abuf + (size_t)row * 768;
    ushort4 r1; r1.x = f2bf(xv.x); r1.y = f2bf(xv.y); r1.z = f2bf(xv.z); r1.w = f2bf(xv.w);
    *(ushort4*)(dst + 256 + lane * 4) = r1;
    ushort4 r2; r2.x = f2bf(0.25f * av.x); r2.y = f2bf(0.25f * av.y);
    r2.z = f2bf(0.25f * av.z); r2.w = f2bf(0.25f * av.w);
    *(ushort4*)(dst + 512 + lane * 4) = r2;
}

// bf16-x variant (fast path): seg1 is a straight bf16 copy.
__global__ __launch_bounds__(256) void pack0b_kernel(
    const unsigned short* __restrict__ xb, const float* __restrict__ attr,
    const int* __restrict__ batch, unsigned short* __restrict__ abuf, int n)
{
    int row = blockIdx.x * 4 + (threadIdx.x >> 6);
    if (row >= n) return;
    const int lane = threadIdx.x & 63;
    ushort4 xv = *(const ushort4*)(xb + (size_t)row * 256 + lane * 4);
    int b = batch[row];
    float4 av = ((const float4*)(attr + (size_t)b * 256))[lane];
    unsigned short* dst = abuf + (size_t)row * 768;
    *(ushort4*)(dst + 256 + lane * 4) = xv;
    ushort4 r2; r2.x = f2bf(0.25f * av.x); r2.y = f2bf(0.25f * av.y);
    r2.z = f2bf(0.25f * av.z); r2.w = f2bf(0.25f * av.w);
    *(ushort4*)(dst + 512 + lane * 4) = r2;
}

// seg1 from bf16 h, seg2 from fp32 attr gather (layer 1).
__global__ __launch_bounds__(256) void pack1_kernel(
    const unsigned short* __restrict__ h, const float* __restrict__ attr,
    const int* __restrict__ batch, unsigned short* __restrict__ abuf, int n)
{
    int row = blockIdx.x * 4 + (threadIdx.x >> 6);
    if (row >= n) return;
    const int lane = threadIdx.x & 63;
    ushort4 hv = *(const ushort4*)(h + (size_t)row * 256 + lane * 4);
    int b = batch[row];
    float4 av = ((const float4*)(attr + (size_t)b * 256))[lane];
    unsigned short* dst = abuf + (size_t)row * 768;
    *(ushort4*)(dst + 256 + lane * 4) = hv;
    ushort4 r2; r2.x = f2bf(0.25f * av.x); r2.y = f2bf(0.25f * av.y);
    r2.z = f2bf(0.25f * av.z); r2.w = f2bf(0.25f * av.w);
    *(ushort4*)(dst + 512 + lane * 4) = r2;
}

// ---------------------------------------------------------------------------
// Weight transpose+cvt: Wt[n][k] bf16, k = [Wl | Wr | Wa]; bias = bl+0.25*ba.
// ---------------------------------------------------------------------------
__global__ __launch_bounds__(256) void wcvt_kernel(
    const float* __restrict__ Wl, const float* __restrict__ Wr,
    const float* __restrict__ Wa, const float* __restrict__ bl,
    const float* __restrict__ ba, unsigned short* __restrict__ Wt,
    float* __restrict__ bias, int N)
{
    int k = blockIdx.x * 256 + threadIdx.x;  // 0..767
    int n = blockIdx.y;
    const float* W; int kk;
    if (k < 256)      { W = Wl; kk = k; }
    else if (k < 512) { W = Wr; kk = k - 256; }
    else              { W = Wa; kk = k - 512; }
    Wt[(size_t)n * 768 + k] = f2bf(W[(size_t)kk * N + n]);
    if (k == 0) bias[n] = bl[n] + 0.25f * ba[n];
}

// ---------------------------------------------------------------------------
// bf16 MFMA GEMM: C = relu(A @ Wt^T + bias). (unchanged)
// ---------------------------------------------------------------------------
template<bool OUT_BF16>
__global__ __launch_bounds__(256) void gemm_mfma_kernel(
    const unsigned short* __restrict__ A,   // [Mpad][768]
    const unsigned short* __restrict__ Wt,  // [N][768]
    const float* __restrict__ bias,         // [N]
    void* __restrict__ Cout, int M, int ldc)
{
    __shared__ unsigned short As[128 * 72];
    __shared__ unsigned short Bs[128 * 72];
    const int tid  = threadIdx.x;
    const int lane = tid & 63;
    const int wave = tid >> 6;
    const int lm   = lane & 15;
    const int quad = lane >> 4;
    const int wm   = (wave & 1) * 64;
    const int wn   = (wave >> 1) * 64;
    const int m0   = blockIdx.x * 128;
    const int n0   = blockIdx.y * 128;

    float4v acc[4][4];
#pragma unroll
    for (int i = 0; i < 4; i++)
#pragma unroll
        for (int j = 0; j < 4; j++)
            acc[i][j] = (float4v){0.f, 0.f, 0.f, 0.f};

    for (int kt = 0; kt < 768; kt += 64) {
#pragma unroll
        for (int i = 0; i < 4; i++) {
            int c = i * 256 + tid;
            int row = c >> 3;
            int col = (c & 7) * 8;
            *(uint4*)&As[row * 72 + col] =
                *(const uint4*)&A[(size_t)(m0 + row) * 768 + kt + col];
            *(uint4*)&Bs[row * 72 + col] =
                *(const uint4*)&Wt[(size_t)(n0 + row) * 768 + kt + col];
        }
        __syncthreads();

#pragma unroll
        for (int h = 0; h < 2; h++) {
            short8 a[4], b[4];
#pragma unroll
            for (int i = 0; i < 4; i++)
                a[i] = *(const short8*)&As[(wm + i * 16 + lm) * 72 + h * 32 + quad * 8];
#pragma unroll
            for (int j = 0; j < 4; j++)
                b[j] = *(const short8*)&Bs[(wn + j * 16 + lm) * 72 + h * 32 + quad * 8];
#pragma unroll
            for (int i = 0; i < 4; i++)
#pragma unroll
                for (int j = 0; j < 4; j++)
                    acc[i][j] = __builtin_amdgcn_mfma_f32_16x16x32_bf16(
                        a[i], b[j], acc[i][j], 0, 0, 0);
        }
        __syncthreads();
    }

    float bcol[4];
#pragma unroll
    for (int j = 0; j < 4; j++) bcol[j] = bias[n0 + wn + j * 16 + lm];

#pragma unroll
    for (int i = 0; i < 4; i++) {
        int rbase = m0 + wm + i * 16 + quad * 4;
#pragma unroll
        for (int j = 0; j < 4; j++) {
            int col = n0 + wn + j * 16 + lm;
#pragma unroll
            for (int r = 0; r < 4; r++) {
                int row = rbase + r;
                if (row < M) {
                    float v = fmaxf(acc[i][j][r] + bcol[j], 0.f);
                    if (OUT_BF16)
                        ((unsigned short*)Cout)[(size_t)row * ldc + col] = f2bf(v);
                    else
                        ((float*)Cout)[(size_t)row * ldc + col] = v;
                }
            }
        }
    }
}

// ---------------------------------------------------------------------------
// Launch
// ---------------------------------------------------------------------------
extern "C" void kernel_launch(void* const* d_in, const int* in_sizes, int n_in,
                              void* d_out, int out_size, void* d_ws, size_t ws_size,
                              hipStream_t stream) {
    const float* x     = (const float*)d_in[0];
    const float* attr  = (const float*)d_in[1];
    const int* src0    = (const int*)d_in[2];
    const int* dst0    = (const int*)d_in[3];
    const int* src1    = (const int*)d_in[4];
    const int* dst1    = (const int*)d_in[5];
    const int* batch0  = (const int*)d_in[6];
    const int* batch1  = (const int*)d_in[7];
    const float* W_l0  = (const float*)d_in[8];
    const float* b_l0  = (const float*)d_in[9];
    const float* W_r0  = (const float*)d_in[10];
    const float* W_l1  = (const float*)d_in[11];
    const float* b_l1  = (const float*)d_in[12];
    const float* W_r1  = (const float*)d_in[13];
    const float* W_a0  = (const float*)d_in[14];
    const float* b_a0  = (const float*)d_in[15];
    const float* W_a1  = (const float*)d_in[16];
    const float* b_a1  = (const float*)d_in[17];
    float* out = (float*)d_out;

    const int N0 = in_sizes[0] / 256;  // 200000
    const int E0 = in_sizes[2];        // 1600000
    const int E1 = in_sizes[4];        // 320000
    const int N1 = in_sizes[6];        // 50000
    const int N2 = in_sizes[7];        // 10000
    const int MP0 = 50048;             // 391*128
    const int MP1 = 10112;             // 79*128
    const int NB0 = (N1 + 1023) / 1024;
    const int NB1 = (N2 + 1023) / 1024;

    const size_t abuf_b = (size_t)MP0 * 768 * 2;     // 76.87 MB
    const size_t xb_b   = (size_t)N0 * 256 * 2;      // 102.4 MB (fast path)
    const size_t h_b    = (size_t)MP0 * 256 * 2;     // 25.6 MB
    const size_t wt_b   = (size_t)256 * 768 * 2 + (size_t)128 * 768 * 2 + 1024 + 512;
    const size_t csr_b  = ((size_t)E0 + (N1 + 1) + N1 + 256) * 4;
    const bool fast = ws_size >= abuf_b + xb_b + wt_b + csr_b;

    char* p = (char*)d_ws;
    unsigned short* abuf = (unsigned short*)p;  p += abuf_b;
    unsigned short* xb;       // bf16 copy of x (fast path only)
    unsigned short* h;        // bf16 hidden layer; aliases xb (xb dead by gemm0)
    if (fast) { xb = (unsigned short*)p; h = xb; p += xb_b; }
    else      { xb = nullptr; h = (unsigned short*)p; p += h_b; }
    unsigned short* Wt0 = (unsigned short*)p; p += (size_t)256 * 768 * 2;
    unsigned short* Wt1 = (unsigned short*)p; p += (size_t)128 * 768 * 2;
    float* bias0 = (float*)p; p += 1024;
    float* bias1 = (float*)p; p += 512;
    int* bsrc0   = (int*)p;
    int* rowptr0 = bsrc0 + E0;
    int* deg0    = rowptr0 + N1 + 1;
    int* part0   = deg0 + N1;
    int* bsrc1   = bsrc0;                 // layer-1 CSR aliases layer-0's
    int* rowptr1 = bsrc1 + E1;
    int* deg1    = rowptr1 + N2 + 1;
    int* part1   = deg1 + N2;

    const int PS0 = (N1 + 7) / 8;      // dst-partition size, layer 0
    const int PS1 = (N2 + 7) / 8;      // dst-partition size, layer 1
    const int NCH0 = (E0 / 4 + 255) / 256;  // edge chunks, layer 0
    const int NCH1 = (E1 / 4 + 255) / 256;  // edge chunks, layer 1

    // ---- layer 0 ----
    hipMemsetAsync(deg0, 0, (size_t)N1 * sizeof(int), stream);
    if (fast)
        xcvt_kernel<<<(N0 * 256 / 4 + 255) / 256, 256, 0, stream>>>(x, xb, N0 * 256 / 4);
    count_kernel<<<NCH0, 256, 0, stream>>>(dst0, deg0, E0);
    partial_kernel<<<NB0, 256, 0, stream>>>(deg0, part0, N1);
    scanpart_kernel<<<1, 256, 0, stream>>>(part0, rowptr0, NB0, N1);
    apply_kernel<<<NB0, 256, 0, stream>>>(deg0, part0, rowptr0, N1);
    bucket_part_kernel<<<NCH0 * 8, 256, 0, stream>>>(src0, dst0, deg0, bsrc0, E0, PS0);
    if (fast) {
        agg_bf16_kernel<<<(N1 + 3) / 4, 256, 0, stream>>>(xb, rowptr0, bsrc0, abuf, 768, N1);
        pack0b_kernel<<<(N1 + 3) / 4, 256, 0, stream>>>(xb, attr, batch0, abuf, N1);
    } else {
        agg_f32_kernel<<<(N1 + 3) / 4, 256, 0, stream>>>(x, rowptr0, bsrc0, abuf, 768, N1);
        pack0_kernel<<<(N1 + 3) / 4, 256, 0, stream>>>(x, attr, batch0, abuf, N1);
    }
    wcvt_kernel<<<dim3(3, 256), 256, 0, stream>>>(W_l0, W_r0, W_a0, b_l0, b_a0,
                                                  Wt0, bias0, 256);
    // gemm0 writes h; on the fast path this overwrites xb, which is dead here.
    gemm_mfma_kernel<true><<<dim3(MP0 / 128, 2), 256, 0, stream>>>(
        abuf, Wt0, bias0, h, MP0, 256);

    // ---- layer 1 ----
    hipMemsetAsync(deg1, 0, (size_t)N2 * sizeof(int), stream);
    count_kernel<<<NCH1, 256, 0, stream>>>(dst1, deg1, E1);
    partial_kernel<<<NB1, 256, 0, stream>>>(deg1, part1, N2);
    scanpart_kernel<<<1, 256, 0, stream>>>(part1, rowptr1, NB1, N2);
    apply_kernel<<<NB1, 256, 0, stream>>>(deg1, part1, rowptr1, N2);
    bucket_part_kernel<<<NCH1 * 8, 256, 0, stream>>>(src1, dst1, deg1, bsrc1, E1, PS1);
    agg_bf16_kernel<<<(N2 + 3) / 4, 256, 0, stream>>>(h, rowptr1, bsrc1, abuf, 768, N2);
    pack1_kernel<<<(N2 + 3) / 4, 256, 0, stream>>>(h, attr, batch1, abuf, N2);
    wcvt_kernel<<<dim3(3, 128), 256, 0, stream>>>(W_l1, W_r1, W_a1, b_l1, b_a1,
                                                  Wt1, bias1, 128);
    gemm_mfma_kernel<false><<<dim3(MP1 / 128, 1), 256, 0, stream>>>(
        abuf, Wt1, bias1, out, N2, 128);
}

// Round 2
// 844.963 us; speedup vs baseline: 1.0910x; 1.0095x over previous
//
#include <hip/hip_runtime.h>

// Problem constants (fixed by the reference):
//   N0=200000, N1=50000, N2=10000, E0=1600000, E1=320000
//   IN_CH=256, HID=256, OUT=128,  K = 3*256 = 768
//
// Round 7:
//  - agg_bf16 was 122us at HBM 43%/VALU 31%/0 MFMA -> latency-bound gather
//    (4x8B loads in flight/wave). Rework: lane owns 8 ch (16B dwordx4),
//    half-wave per edge (lanes 0-31 even edge, 32-63 odd edge), 8 edges in
//    flight, __shfl_xor(32) combine. Pack (seg1 copy + 0.25*attr gather)
//    fused into the same kernel (half0 does seg1, half1 does seg2).
//  - count_kernel had the same cross-XCD random-atomic pattern that made the
//    old bucket 153us; apply the same 8-way XCD dst-partition trick.

typedef __attribute__((ext_vector_type(8))) short short8;
typedef __attribute__((ext_vector_type(4))) float float4v;

__device__ __forceinline__ unsigned short f2bf(float f) {
    union { float f; unsigned int u; } c; c.f = f;
    unsigned int r = (c.u + 0x7FFFu + ((c.u >> 16) & 1u)) >> 16;  // RNE
    return (unsigned short)r;
}
__device__ __forceinline__ float bf2f(unsigned short u) {
    union { unsigned int u; float f; } c; c.u = ((unsigned int)u) << 16;
    return c.f;
}
__device__ __forceinline__ float bflo(unsigned int u) {
    union { unsigned int u; float f; } c; c.u = u << 16;
    return c.f;
}
__device__ __forceinline__ float bfhi(unsigned int u) {
    union { unsigned int u; float f; } c; c.u = u & 0xFFFF0000u;
    return c.f;
}
__device__ __forceinline__ unsigned int bfpack(float lo, float hi) {
    return ((unsigned int)f2bf(hi) << 16) | (unsigned int)f2bf(lo);
}

// ---------------------------------------------------------------------------
// fp32 -> bf16 streaming convert (4 elems/thread).
// ---------------------------------------------------------------------------
__global__ __launch_bounds__(256) void xcvt_kernel(
    const float* __restrict__ x, unsigned short* __restrict__ xb, int n4)
{
    int i = blockIdx.x * 256 + threadIdx.x;
    if (i < n4) {
        float4 v = ((const float4*)x)[i];
        ushort4 r;
        r.x = f2bf(v.x); r.y = f2bf(v.y); r.z = f2bf(v.z); r.w = f2bf(v.w);
        ((ushort4*)xb)[i] = r;
    }
}

// ---------------------------------------------------------------------------
// CSR build step 1: degree histogram, XCD-partitioned (blockIdx&7 tracks the
// round-robin block->XCD mapping; each partition's counters stay in ONE L2).
// ---------------------------------------------------------------------------
__global__ __launch_bounds__(256) void count_part_kernel(
    const int* __restrict__ dst, int* __restrict__ deg, int E, int ps)
{
    const int part = blockIdx.x & 7;
    const int lo = part * ps;
    const int hi = lo + ps;
    int i = ((blockIdx.x >> 3) * 256 + threadIdx.x) * 4;
    if (i + 3 < E) {
        int4 d = *(const int4*)&dst[i];
        if (d.x >= lo && d.x < hi) atomicAdd(&deg[d.x], 1);
        if (d.y >= lo && d.y < hi) atomicAdd(&deg[d.y], 1);
        if (d.z >= lo && d.z < hi) atomicAdd(&deg[d.z], 1);
        if (d.w >= lo && d.w < hi) atomicAdd(&deg[d.w], 1);
    } else {
        for (int k = i; k < E; k++) {
            int dv = dst[k];
            if (dv >= lo && dv < hi) atomicAdd(&deg[dv], 1);
        }
    }
}

// ---------------------------------------------------------------------------
// CSR build step 2a: per-block (1024-elem) partial sums of deg.
// ---------------------------------------------------------------------------
__global__ __launch_bounds__(256) void partial_kernel(
    const int* __restrict__ deg, int* __restrict__ part, int n)
{
    __shared__ int sm[256];
    const int base = blockIdx.x * 1024;
    const int t = threadIdx.x;
    int s = 0;
#pragma unroll
    for (int i = 0; i < 4; i++) {
        int idx = base + t + i * 256;
        if (idx < n) s += deg[idx];
    }
    sm[t] = s;
    __syncthreads();
    for (int off = 128; off > 0; off >>= 1) {
        if (t < off) sm[t] += sm[t + off];
        __syncthreads();
    }
    if (t == 0) part[blockIdx.x] = sm[0];
}

// ---------------------------------------------------------------------------
// CSR build step 2b: exclusive scan of block partials (nb <= 256).
// ---------------------------------------------------------------------------
__global__ __launch_bounds__(256) void scanpart_kernel(
    int* __restrict__ part, int* __restrict__ rowptr, int nb, int n)
{
    __shared__ int sm[256];
    const int t = threadIdx.x;
    sm[t] = (t < nb) ? part[t] : 0;
    __syncthreads();
    if (t == 0) {
        int acc = 0;
        for (int i = 0; i < nb; i++) { int v = sm[i]; sm[i] = acc; acc += v; }
        rowptr[n] = acc;
    }
    __syncthreads();
    if (t < nb) part[t] = sm[t];
}

// ---------------------------------------------------------------------------
// CSR build step 2c: intra-block exclusive scan; rowptr + cursor init.
// ---------------------------------------------------------------------------
__global__ __launch_bounds__(256) void apply_kernel(
    int* __restrict__ deg, const int* __restrict__ part,
    int* __restrict__ rowptr, int n)
{
    __shared__ int sm[256];
    const int base = blockIdx.x * 1024;
    const int t = threadIdx.x;
    const int i0 = base + t * 4;

    int4 d = {0, 0, 0, 0};
    if (i0 + 3 < n) {
        d = *(const int4*)&deg[i0];
    } else {
        if (i0 + 0 < n) d.x = deg[i0 + 0];
        if (i0 + 1 < n) d.y = deg[i0 + 1];
        if (i0 + 2 < n) d.z = deg[i0 + 2];
        if (i0 + 3 < n) d.w = deg[i0 + 3];
    }
    const int ts = d.x + d.y + d.z + d.w;
    sm[t] = ts;
    __syncthreads();
    for (int off = 1; off < 256; off <<= 1) {
        int u = (t >= off) ? sm[t - off] : 0;
        __syncthreads();
        sm[t] += u;
        __syncthreads();
    }
    int pref = part[blockIdx.x] + sm[t] - ts;

    int p0 = pref;
    int p1 = p0 + d.x;
    int p2 = p1 + d.y;
    int p3 = p2 + d.z;
    if (i0 + 0 < n) { rowptr[i0 + 0] = p0; deg[i0 + 0] = p0; }
    if (i0 + 1 < n) { rowptr[i0 + 1] = p1; deg[i0 + 1] = p1; }
    if (i0 + 2 < n) { rowptr[i0 + 2] = p2; deg[i0 + 2] = p2; }
    if (i0 + 3 < n) { rowptr[i0 + 3] = p3; deg[i0 + 3] = p3; }
}

// ---------------------------------------------------------------------------
// CSR build step 3: bucket src ids by dst, XCD-partitioned.
// ---------------------------------------------------------------------------
__global__ __launch_bounds__(256) void bucket_part_kernel(
    const int* __restrict__ src, const int* __restrict__ dst,
    int* __restrict__ pos, int* __restrict__ bsrc, int E, int ps)
{
    const int part = blockIdx.x & 7;
    const int lo = part * ps;
    const int hi = lo + ps;
    int i = ((blockIdx.x >> 3) * 256 + threadIdx.x) * 4;
    if (i + 3 < E) {
        int4 d = *(const int4*)&dst[i];
        int4 s = *(const int4*)&src[i];
        if (d.x >= lo && d.x < hi) { int p = atomicAdd(&pos[d.x], 1); bsrc[p] = s.x; }
        if (d.y >= lo && d.y < hi) { int p = atomicAdd(&pos[d.y], 1); bsrc[p] = s.y; }
        if (d.z >= lo && d.z < hi) { int p = atomicAdd(&pos[d.z], 1); bsrc[p] = s.z; }
        if (d.w >= lo && d.w < hi) { int p = atomicAdd(&pos[d.w], 1); bsrc[p] = s.w; }
    } else {
        for (int k = i; k < E; k++) {
            int dv = dst[k];
            if (dv >= lo && dv < hi) {
                int p = atomicAdd(&pos[dv], 1);
                bsrc[p] = src[k];
            }
        }
    }
}

// ---------------------------------------------------------------------------
// Aggregation, fp32 source -> bf16 mean (fallback path only).
// ---------------------------------------------------------------------------
__global__ __launch_bounds__(256) void agg_f32_kernel(
    const float* __restrict__ xsrc,
    const int* __restrict__ rowptr,
    const int* __restrict__ bsrc,
    unsigned short* __restrict__ outp,
    int pitch, int n)
{
    int row = blockIdx.x * 4 + (threadIdx.x >> 6);
    if (row >= n) return;
    const int lane = threadIdx.x & 63;
    const int beg = rowptr[row];
    const int end = rowptr[row + 1];

    float4 a0 = {0.f, 0.f, 0.f, 0.f};
    float4 a1 = {0.f, 0.f, 0.f, 0.f};
    float4 a2 = {0.f, 0.f, 0.f, 0.f};
    float4 a3 = {0.f, 0.f, 0.f, 0.f};
    int e = beg;
    for (; e + 3 < end; e += 4) {
        int s0 = bsrc[e + 0];
        int s1 = bsrc[e + 1];
        int s2 = bsrc[e + 2];
        int s3 = bsrc[e + 3];
        float4 v0 = ((const float4*)(xsrc + (size_t)s0 * 256))[lane];
        float4 v1 = ((const float4*)(xsrc + (size_t)s1 * 256))[lane];
        float4 v2 = ((const float4*)(xsrc + (size_t)s2 * 256))[lane];
        float4 v3 = ((const float4*)(xsrc + (size_t)s3 * 256))[lane];
        a0.x += v0.x; a0.y += v0.y; a0.z += v0.z; a0.w += v0.w;
        a1.x += v1.x; a1.y += v1.y; a1.z += v1.z; a1.w += v1.w;
        a2.x += v2.x; a2.y += v2.y; a2.z += v2.z; a2.w += v2.w;
        a3.x += v3.x; a3.y += v3.y; a3.z += v3.z; a3.w += v3.w;
    }
    for (; e < end; e++) {
        int s0 = bsrc[e];
        float4 v0 = ((const float4*)(xsrc + (size_t)s0 * 256))[lane];
        a0.x += v0.x; a0.y += v0.y; a0.z += v0.z; a0.w += v0.w;
    }
    float inv = 1.0f / fmaxf((float)(end - beg), 1.0f);
    ushort4 r;
    r.x = f2bf((a0.x + a1.x + a2.x + a3.x) * inv);
    r.y = f2bf((a0.y + a1.y + a2.y + a3.y) * inv);
    r.z = f2bf((a0.z + a1.z + a2.z + a3.z) * inv);
    r.w = f2bf((a0.w + a1.w + a2.w + a3.w) * inv);
    *(ushort4*)(outp + (size_t)row * pitch + lane * 4) = r;
}

// ---------------------------------------------------------------------------
// Fused aggregation + pack, bf16 source. One wave per dst row. Lane owns 8
// channels (16B dwordx4); lanes 0-31 process even edges, 32-63 odd edges
// (8 edges in flight), __shfl_xor(32) combines the halves. Epilogue: half0
// stores mean (seg0) + copies seg1 (hseg[row]); half1 gathers attr[batch]
// and stores 0.25*attr (seg2).
// ---------------------------------------------------------------------------
__global__ __launch_bounds__(256) void agg_pack_kernel(
    const unsigned short* __restrict__ hsrc,  // gather source [*, 256] bf16
    const unsigned short* __restrict__ hseg,  // seg1 source   [n, 256] bf16
    const float* __restrict__ attr,           // [N0, 256] fp32
    const int* __restrict__ batch,            // [n]
    const int* __restrict__ rowptr,
    const int* __restrict__ bsrc,
    unsigned short* __restrict__ outp,        // [n, 768] bf16
    int n)
{
    int row = blockIdx.x * 4 + (threadIdx.x >> 6);
    if (row >= n) return;
    const int wl   = threadIdx.x & 63;
    const int half = wl >> 5;        // 0: even edges, 1: odd edges
    const int l    = wl & 31;        // channel-group: ch [l*8, l*8+8)

    const int beg = rowptr[row];
    const int end = rowptr[row + 1];

    float acc[8];
#pragma unroll
    for (int k = 0; k < 8; k++) acc[k] = 0.f;

    const unsigned short* gbase = hsrc + (size_t)l * 8;

    int e = beg;
    for (; e + 7 < end; e += 8) {
        int s0 = bsrc[e + 0 + half];
        int s1 = bsrc[e + 2 + half];
        int s2 = bsrc[e + 4 + half];
        int s3 = bsrc[e + 6 + half];
        uint4 u0 = *(const uint4*)(gbase + (size_t)s0 * 256);
        uint4 u1 = *(const uint4*)(gbase + (size_t)s1 * 256);
        uint4 u2 = *(const uint4*)(gbase + (size_t)s2 * 256);
        uint4 u3 = *(const uint4*)(gbase + (size_t)s3 * 256);
        acc[0] += bflo(u0.x); acc[1] += bfhi(u0.x);
        acc[2] += bflo(u0.y); acc[3] += bfhi(u0.y);
        acc[4] += bflo(u0.z); acc[5] += bfhi(u0.z);
        acc[6] += bflo(u0.w); acc[7] += bfhi(u0.w);
        acc[0] += bflo(u1.x); acc[1] += bfhi(u1.x);
        acc[2] += bflo(u1.y); acc[3] += bfhi(u1.y);
        acc[4] += bflo(u1.z); acc[5] += bfhi(u1.z);
        acc[6] += bflo(u1.w); acc[7] += bfhi(u1.w);
        acc[0] += bflo(u2.x); acc[1] += bfhi(u2.x);
        acc[2] += bflo(u2.y); acc[3] += bfhi(u2.y);
        acc[4] += bflo(u2.z); acc[5] += bfhi(u2.z);
        acc[6] += bflo(u2.w); acc[7] += bfhi(u2.w);
        acc[0] += bflo(u3.x); acc[1] += bfhi(u3.x);
        acc[2] += bflo(u3.y); acc[3] += bfhi(u3.y);
        acc[4] += bflo(u3.z); acc[5] += bfhi(u3.z);
        acc[6] += bflo(u3.w); acc[7] += bfhi(u3.w);
    }
    for (; e + 1 < end; e += 2) {
        int s = bsrc[e + half];
        uint4 u = *(const uint4*)(gbase + (size_t)s * 256);
        acc[0] += bflo(u.x); acc[1] += bfhi(u.x);
        acc[2] += bflo(u.y); acc[3] += bfhi(u.y);
        acc[4] += bflo(u.z); acc[5] += bfhi(u.z);
        acc[6] += bflo(u.w); acc[7] += bfhi(u.w);
    }
    if (e < end && half == 0) {
        int s = bsrc[e];
        uint4 u = *(const uint4*)(gbase + (size_t)s * 256);
        acc[0] += bflo(u.x); acc[1] += bfhi(u.x);
        acc[2] += bflo(u.y); acc[3] += bfhi(u.y);
        acc[4] += bflo(u.z); acc[5] += bfhi(u.z);
        acc[6] += bflo(u.w); acc[7] += bfhi(u.w);
    }

    // combine halves: both halves end with the full sum
#pragma unroll
    for (int k = 0; k < 8; k++) acc[k] += __shfl_xor(acc[k], 32);

    const float inv = 1.0f / fmaxf((float)(end - beg), 1.0f);
    unsigned short* drow = outp + (size_t)row * 768;

    if (half == 0) {
        uint4 r;
        r.x = bfpack(acc[0] * inv, acc[1] * inv);
        r.y = bfpack(acc[2] * inv, acc[3] * inv);
        r.z = bfpack(acc[4] * inv, acc[5] * inv);
        r.w = bfpack(acc[6] * inv, acc[7] * inv);
        *(uint4*)(drow + l * 8) = r;
        // seg1: straight bf16 copy of hseg[row]
        *(uint4*)(drow + 256 + l * 8) =
            *(const uint4*)(hseg + (size_t)row * 256 + l * 8);
    } else {
        int b = batch[row];
        const float* arow = attr + (size_t)b * 256 + l * 8;
        float4 a0 = *(const float4*)(arow);
        float4 a1 = *(const float4*)(arow + 4);
        uint4 r;
        r.x = bfpack(0.25f * a0.x, 0.25f * a0.y);
        r.y = bfpack(0.25f * a0.z, 0.25f * a0.w);
        r.z = bfpack(0.25f * a1.x, 0.25f * a1.y);
        r.w = bfpack(0.25f * a1.z, 0.25f * a1.w);
        *(uint4*)(drow + 512 + l * 8) = r;
    }
}

// ---------------------------------------------------------------------------
// Pack seg1 (x_dst) + seg2 (0.25*attr[batch]). fp32-x variant (fallback).
// ---------------------------------------------------------------------------
__global__ __launch_bounds__(256) void pack0_kernel(
    const float* __restrict__ x, const float* __restrict__ attr,
    const int* __restrict__ batch, unsigned short* __restrict__ abuf, int n)
{
    int row = blockIdx.x * 4 + (threadIdx.x >> 6);
    if (row >= n) return;
    const int lane = threadIdx.x & 63;
    float4 xv = ((const float4*)(x + (size_t)row * 256))[lane];
    int b = batch[row];
    float4 av = ((const float4*)(attr + (size_t)b * 256))[lane];
    unsigned short* dst = abuf + (size_t)row * 768;
    ushort4 r1; r1.x = f2bf(xv.x); r1.y = f2bf(xv.y); r1.z = f2bf(xv.z); r1.w = f2bf(xv.w);
    *(ushort4*)(dst + 256 + lane * 4) = r1;
    ushort4 r2; r2.x = f2bf(0.25f * av.x); r2.y = f2bf(0.25f * av.y);
    r2.z = f2bf(0.25f * av.z); r2.w = f2bf(0.25f * av.w);
    *(ushort4*)(dst + 512 + lane * 4) = r2;
}

// ---------------------------------------------------------------------------
// Weight transpose+cvt: Wt[n][k] bf16, k = [Wl | Wr | Wa]; bias = bl+0.25*ba.
// ---------------------------------------------------------------------------
__global__ __launch_bounds__(256) void wcvt_kernel(
    const float* __restrict__ Wl, const float* __restrict__ Wr,
    const float* __restrict__ Wa, const float* __restrict__ bl,
    const float* __restrict__ ba, unsigned short* __restrict__ Wt,
    float* __restrict__ bias, int N)
{
    int k = blockIdx.x * 256 + threadIdx.x;  // 0..767
    int n = blockIdx.y;
    const float* W; int kk;
    if (k < 256)      { W = Wl; kk = k; }
    else if (k < 512) { W = Wr; kk = k - 256; }
    else              { W = Wa; kk = k - 512; }
    Wt[(size_t)n * 768 + k] = f2bf(W[(size_t)kk * N + n]);
    if (k == 0) bias[n] = bl[n] + 0.25f * ba[n];
}

// ---------------------------------------------------------------------------
// bf16 MFMA GEMM: C = relu(A @ Wt^T + bias). (unchanged)
// ---------------------------------------------------------------------------
template<bool OUT_BF16>
__global__ __launch_bounds__(256) void gemm_mfma_kernel(
    const unsigned short* __restrict__ A,   // [Mpad][768]
    const unsigned short* __restrict__ Wt,  // [N][768]
    const float* __restrict__ bias,         // [N]
    void* __restrict__ Cout, int M, int ldc)
{
    __shared__ unsigned short As[128 * 72];
    __shared__ unsigned short Bs[128 * 72];
    const int tid  = threadIdx.x;
    const int lane = tid & 63;
    const int wave = tid >> 6;
    const int lm   = lane & 15;
    const int quad = lane >> 4;
    const int wm   = (wave & 1) * 64;
    const int wn   = (wave >> 1) * 64;
    const int m0   = blockIdx.x * 128;
    const int n0   = blockIdx.y * 128;

    float4v acc[4][4];
#pragma unroll
    for (int i = 0; i < 4; i++)
#pragma unroll
        for (int j = 0; j < 4; j++)
            acc[i][j] = (float4v){0.f, 0.f, 0.f, 0.f};

    for (int kt = 0; kt < 768; kt += 64) {
#pragma unroll
        for (int i = 0; i < 4; i++) {
            int c = i * 256 + tid;
            int row = c >> 3;
            int col = (c & 7) * 8;
            *(uint4*)&As[row * 72 + col] =
                *(const uint4*)&A[(size_t)(m0 + row) * 768 + kt + col];
            *(uint4*)&Bs[row * 72 + col] =
                *(const uint4*)&Wt[(size_t)(n0 + row) * 768 + kt + col];
        }
        __syncthreads();

#pragma unroll
        for (int h = 0; h < 2; h++) {
            short8 a[4], b[4];
#pragma unroll
            for (int i = 0; i < 4; i++)
                a[i] = *(const short8*)&As[(wm + i * 16 + lm) * 72 + h * 32 + quad * 8];
#pragma unroll
            for (int j = 0; j < 4; j++)
                b[j] = *(const short8*)&Bs[(wn + j * 16 + lm) * 72 + h * 32 + quad * 8];
#pragma unroll
            for (int i = 0; i < 4; i++)
#pragma unroll
                for (int j = 0; j < 4; j++)
                    acc[i][j] = __builtin_amdgcn_mfma_f32_16x16x32_bf16(
                        a[i], b[j], acc[i][j], 0, 0, 0);
        }
        __syncthreads();
    }

    float bcol[4];
#pragma unroll
    for (int j = 0; j < 4; j++) bcol[j] = bias[n0 + wn + j * 16 + lm];

#pragma unroll
    for (int i = 0; i < 4; i++) {
        int rbase = m0 + wm + i * 16 + quad * 4;
#pragma unroll
        for (int j = 0; j < 4; j++) {
            int col = n0 + wn + j * 16 + lm;
#pragma unroll
            for (int r = 0; r < 4; r++) {
                int row = rbase + r;
                if (row < M) {
                    float v = fmaxf(acc[i][j][r] + bcol[j], 0.f);
                    if (OUT_BF16)
                        ((unsigned short*)Cout)[(size_t)row * ldc + col] = f2bf(v);
                    else
                        ((float*)Cout)[(size_t)row * ldc + col] = v;
                }
            }
        }
    }
}

// ---------------------------------------------------------------------------
// Launch
// ---------------------------------------------------------------------------
extern "C" void kernel_launch(void* const* d_in, const int* in_sizes, int n_in,
                              void* d_out, int out_size, void* d_ws, size_t ws_size,
                              hipStream_t stream) {
    const float* x     = (const float*)d_in[0];
    const float* attr  = (const float*)d_in[1];
    const int* src0    = (const int*)d_in[2];
    const int* dst0    = (const int*)d_in[3];
    const int* src1    = (const int*)d_in[4];
    const int* dst1    = (const int*)d_in[5];
    const int* batch0  = (const int*)d_in[6];
    const int* batch1  = (const int*)d_in[7];
    const float* W_l0  = (const float*)d_in[8];
    const float* b_l0  = (const float*)d_in[9];
    const float* W_r0  = (const float*)d_in[10];
    const float* W_l1  = (const float*)d_in[11];
    const float* b_l1  = (const float*)d_in[12];
    const float* W_r1  = (const float*)d_in[13];
    const float* W_a0  = (const float*)d_in[14];
    const float* b_a0  = (const float*)d_in[15];
    const float* W_a1  = (const float*)d_in[16];
    const float* b_a1  = (const float*)d_in[17];
    float* out = (float*)d_out;

    const int N0 = in_sizes[0] / 256;  // 200000
    const int E0 = in_sizes[2];        // 1600000
    const int E1 = in_sizes[4];        // 320000
    const int N1 = in_sizes[6];        // 50000
    const int N2 = in_sizes[7];        // 10000
    const int MP0 = 50048;             // 391*128
    const int MP1 = 10112;             // 79*128
    const int NB0 = (N1 + 1023) / 1024;
    const int NB1 = (N2 + 1023) / 1024;

    const size_t abuf_b = (size_t)MP0 * 768 * 2;     // 76.87 MB
    const size_t xb_b   = (size_t)N0 * 256 * 2;      // 102.4 MB (fast path)
    const size_t h_b    = (size_t)MP0 * 256 * 2;     // 25.6 MB
    const size_t wt_b   = (size_t)256 * 768 * 2 + (size_t)128 * 768 * 2 + 1024 + 512;
    const size_t csr_b  = ((size_t)E0 + (N1 + 1) + N1 + 256) * 4;
    const bool fast = ws_size >= abuf_b + xb_b + wt_b + csr_b;

    char* p = (char*)d_ws;
    unsigned short* abuf = (unsigned short*)p;  p += abuf_b;
    unsigned short* xb;       // bf16 copy of x (fast path only)
    unsigned short* h;        // bf16 hidden layer; aliases xb (xb dead by gemm0)
    if (fast) { xb = (unsigned short*)p; h = xb; p += xb_b; }
    else      { xb = nullptr; h = (unsigned short*)p; p += h_b; }
    unsigned short* Wt0 = (unsigned short*)p; p += (size_t)256 * 768 * 2;
    unsigned short* Wt1 = (unsigned short*)p; p += (size_t)128 * 768 * 2;
    float* bias0 = (float*)p; p += 1024;
    float* bias1 = (float*)p; p += 512;
    int* bsrc0   = (int*)p;
    int* rowptr0 = bsrc0 + E0;
    int* deg0    = rowptr0 + N1 + 1;
    int* part0   = deg0 + N1;
    int* bsrc1   = bsrc0;                 // layer-1 CSR aliases layer-0's
    int* rowptr1 = bsrc1 + E1;
    int* deg1    = rowptr1 + N2 + 1;
    int* part1   = deg1 + N2;

    const int PS0 = (N1 + 7) / 8;      // dst-partition size, layer 0
    const int PS1 = (N2 + 7) / 8;      // dst-partition size, layer 1
    const int NCH0 = (E0 / 4 + 255) / 256;  // edge chunks, layer 0
    const int NCH1 = (E1 / 4 + 255) / 256;  // edge chunks, layer 1

    // ---- layer 0 ----
    hipMemsetAsync(deg0, 0, (size_t)N1 * sizeof(int), stream);
    if (fast)
        xcvt_kernel<<<(N0 * 256 / 4 + 255) / 256, 256, 0, stream>>>(x, xb, N0 * 256 / 4);
    count_part_kernel<<<NCH0 * 8, 256, 0, stream>>>(dst0, deg0, E0, PS0);
    partial_kernel<<<NB0, 256, 0, stream>>>(deg0, part0, N1);
    scanpart_kernel<<<1, 256, 0, stream>>>(part0, rowptr0, NB0, N1);
    apply_kernel<<<NB0, 256, 0, stream>>>(deg0, part0, rowptr0, N1);
    bucket_part_kernel<<<NCH0 * 8, 256, 0, stream>>>(src0, dst0, deg0, bsrc0, E0, PS0);
    if (fast) {
        agg_pack_kernel<<<(N1 + 3) / 4, 256, 0, stream>>>(
            xb, xb, attr, batch0, rowptr0, bsrc0, abuf, N1);
    } else {
        agg_f32_kernel<<<(N1 + 3) / 4, 256, 0, stream>>>(x, rowptr0, bsrc0, abuf, 768, N1);
        pack0_kernel<<<(N1 + 3) / 4, 256, 0, stream>>>(x, attr, batch0, abuf, N1);
    }
    wcvt_kernel<<<dim3(3, 256), 256, 0, stream>>>(W_l0, W_r0, W_a0, b_l0, b_a0,
                                                  Wt0, bias0, 256);
    // gemm0 writes h; on the fast path this overwrites xb, which is dead here.
    gemm_mfma_kernel<true><<<dim3(MP0 / 128, 2), 256, 0, stream>>>(
        abuf, Wt0, bias0, h, MP0, 256);

    // ---- layer 1 ----
    hipMemsetAsync(deg1, 0, (size_t)N2 * sizeof(int), stream);
    count_part_kernel<<<NCH1 * 8, 256, 0, stream>>>(dst1, deg1, E1, PS1);
    partial_kernel<<<NB1, 256, 0, stream>>>(deg1, part1, N2);
    scanpart_kernel<<<1, 256, 0, stream>>>(part1, rowptr1, NB1, N2);
    apply_kernel<<<NB1, 256, 0, stream>>>(deg1, part1, rowptr1, N2);
    bucket_part_kernel<<<NCH1 * 8, 256, 0, stream>>>(src1, dst1, deg1, bsrc1, E1, PS1);
    agg_pack_kernel<<<(N2 + 3) / 4, 256, 0, stream>>>(
        h, h, attr, batch1, rowptr1, bsrc1, abuf, N2);
    wcvt_kernel<<<dim3(3, 128), 256, 0, stream>>>(W_l1, W_r1, W_a1, b_l1, b_a1,
                                                  Wt1, bias1, 128);
    gemm_mfma_kernel<false><<<dim3(MP1 / 128, 1), 256, 0, stream>>>(
        abuf, Wt1, bias1, out, N2, 128);
}